// Round 6
// baseline (395.315 us; speedup 1.0000x reference)
//
#include <hip/hip_runtime.h>
#include <math.h>

#define DIMC 64
#define NE 512
#define HWSZ 4096              // 64*64
#define NPTS 131072            // B*H*W
#define DECAYF 0.99f
#define OMD 0.01f
#define EPSF 1e-5f

// output offsets (floats) — out0 is [32,64,64,64] = 8388608 elements
#define O0 0
#define O1 8388608                 // diff scalar
#define O2 8388609                 // embed_ind [32,64,64]
#define O3 8519681                 // new_cluster_size [512]
#define O4 8520193                 // new_dictionary_avg [64,512]
#define O5 8552961                 // new_dictionary [64,512]
#define O6 8585729                 // mean_D scalar

// ws float layout
#define WS_DIFF   0
#define WS_ESUM   64                       // [c][j] 64*512 (reduced)
#define WS_COUNTS (64+32768)               // 512 (reduced)
#define WS_DT     (64+32768+512)           // [j][c] transposed dict, 32768
#define WS_NORM   (WS_DT+32768)            // 512: -0.5*||d_j||^2
#define WS_PART   (WS_NORM+512)            // NBLK x 33280 partials
#define PART_STRIDE 33280                  // 32768 esum + 512 counts
#define NBLK 256
#define WS_NEED_BYTES ((size_t)(WS_PART + (size_t)NBLK * PART_STRIDE) * 4)

// -------- K1: transpose dictionary to [j][c] + negated half-norms --------
__global__ void k_prep(const float* __restrict__ dict, float* __restrict__ ws) {
    int j = blockIdx.x, c = threadIdx.x;
    float v = dict[c * NE + j];
    ws[WS_DT + j * DIMC + c] = v;
    float s = v * v;
    #pragma unroll
    for (int off = 32; off > 0; off >>= 1) s += __shfl_down(s, off);
    if (c == 0) ws[WS_NORM + j] = -0.5f * s;
}

// load one dict row (256 B) into a register buffer (static indices only)
#define LOADROW(BUF, JJ) do {                                            \
    const float4* rp_ = (const float4*)(dptr + (size_t)(JJ) * DIMC);     \
    _Pragma("unroll")                                                    \
    for (int k_ = 0; k_ < 16; ++k_) BUF[k_] = rp_[k_];                   \
} while (0)

// score row JJ from BUF — fmaf chain identical to the passing r5 kernel
#define SCORE(BUF, JJ) do {                                              \
    float a0 = 0.f, a1 = 0.f, a2 = 0.f, a3 = 0.f;                        \
    _Pragma("unroll")                                                    \
    for (int c4_ = 0; c4_ < 16; ++c4_) {                                 \
        float4 r_ = BUF[c4_];                                            \
        const int cb_ = 4 * c4_;                                         \
        a0 = fmaf(r_.x, f0[cb_ + 0], a0);                                \
        a1 = fmaf(r_.y, f0[cb_ + 1], a1);                                \
        a2 = fmaf(r_.z, f0[cb_ + 2], a2);                                \
        a3 = fmaf(r_.w, f0[cb_ + 3], a3);                                \
    }                                                                    \
    float sc_ = ((a0 + a1) + (a2 + a3)) + nptr[JJ];                      \
    if (sc_ > best0) { best0 = sc_; bi0 = (JJ); }                        \
} while (0)

// -------- K2: assignment + quantize + per-block partial stats --------
// 256 blocks x 512 threads; dict rows streamed via VMEM (L2-resident),
// double-buffered in registers so loads pipeline under the fmaf chain.
__global__ __launch_bounds__(512, 1) void k_assign(
        const float* __restrict__ x, float* __restrict__ ws,
        float* __restrict__ out, int use_part) {
    extern __shared__ float lds[];
    float* esum = lds;                  // 32768 f: esum_t [c][j]
    int*   lhist = (int*)(lds + 32768); // 512
    float* lred  = lds + 33280;         // 8

    const int tid = threadIdx.x;

    // zero esum + hist
    {
        float4* e4 = (float4*)esum;
        float4 z = {0.f, 0.f, 0.f, 0.f};
        #pragma unroll
        for (int k = 0; k < 16; ++k) e4[tid + 512 * k] = z;
        lhist[tid] = 0;
    }
    __syncthreads();

    const int n0 = blockIdx.x * 512 + tid;
    const int b = n0 >> 12, hw0 = n0 & 4095;
    const float* xp = x + (size_t)b * (DIMC * HWSZ) + hw0;
    float f0[DIMC];
    #pragma unroll
    for (int c = 0; c < DIMC; ++c) f0[c] = xp[c * HWSZ];

    const float* dptr = ws + WS_DT;
    const float* nptr = ws + WS_NORM;

    float best0 = -3.4e38f;
    int bi0 = 0;
    float4 bA[16], bB[16];
    LOADROW(bA, 0);
    for (int j = 0; j < NE; j += 2) {
        LOADROW(bB, j + 1);
        SCORE(bA, j);
        LOADROW(bA, j + 2);   // j=510 -> row 512 reads WS_NORM region: benign
        SCORE(bB, j + 1);
    }

    atomicAdd(&lhist[bi0], 1);
    out[O2 + n0] = (float)bi0;

    // quantize gather from global dictT (L2-resident) + NCHW write + diff
    float ssum = 0.f;
    float* o0 = out + O0 + (size_t)b * (DIMC * HWSZ) + hw0;
    const float4* q40 = (const float4*)(dptr + (size_t)bi0 * DIMC);
    #pragma unroll
    for (int c4 = 0; c4 < 16; ++c4) {
        float4 qa = q40[c4];
        const int cb = 4 * c4;
        o0[(cb + 0) * HWSZ] = qa.x;
        o0[(cb + 1) * HWSZ] = qa.y;
        o0[(cb + 2) * HWSZ] = qa.z;
        o0[(cb + 3) * HWSZ] = qa.w;
        float d;
        d = qa.x - f0[cb + 0]; ssum = fmaf(d, d, ssum);
        d = qa.y - f0[cb + 1]; ssum = fmaf(d, d, ssum);
        d = qa.z - f0[cb + 2]; ssum = fmaf(d, d, ssum);
        d = qa.w - f0[cb + 3]; ssum = fmaf(d, d, ssum);
    }

    // scatter: banks spread by bidx (esum[c*512 + j], bank = j & 31)
    #pragma unroll
    for (int c = 0; c < DIMC; ++c) atomicAdd(&esum[c * NE + bi0], f0[c]);
    __syncthreads();

    if (use_part) {
        float* part = ws + WS_PART + (size_t)blockIdx.x * PART_STRIDE;
        float4* p4 = (float4*)part;
        const float4* e4 = (const float4*)esum;
        #pragma unroll
        for (int k = 0; k < 16; ++k) p4[tid + 512 * k] = e4[tid + 512 * k];
        part[32768 + tid] = (float)lhist[tid];
    } else {
        #pragma unroll
        for (int k = 0; k < 64; ++k)
            atomicAdd(&ws[WS_ESUM + tid + 512 * k], esum[tid + 512 * k]);
        atomicAdd(&ws[WS_COUNTS + tid], (float)lhist[tid]);
    }

    // diff reduction (8 waves)
    #pragma unroll
    for (int off = 32; off > 0; off >>= 1) ssum += __shfl_down(ssum, off);
    if ((tid & 63) == 0) lred[tid >> 6] = ssum;
    __syncthreads();
    if (tid == 0) {
        float t = 0.f;
        #pragma unroll
        for (int w = 0; w < 8; ++w) t += lred[w];
        atomicAdd(ws + WS_DIFF, t);
    }
}

// -------- K2b: tree-reduce per-block partials into WS_ESUM/WS_COUNTS --------
// 65 blocks x 128 threads = 8320 float4 positions (33280 floats)
__global__ void k_reduce(float* __restrict__ ws) {
    const int gid = blockIdx.x * 128 + threadIdx.x;   // [0, 8320)
    const float4* src = (const float4*)(ws + WS_PART);
    float4 acc = {0.f, 0.f, 0.f, 0.f};
    #pragma unroll 4
    for (int p = 0; p < NBLK; ++p) {
        float4 v = src[(size_t)p * (PART_STRIDE / 4) + gid];
        acc.x += v.x; acc.y += v.y; acc.z += v.z; acc.w += v.w;
    }
    ((float4*)(ws + WS_ESUM))[gid] = acc;   // COUNTS region follows ESUM contiguously
}

// -------- K3: finalize EMA buffers / outputs --------
__global__ void k_final(const float* __restrict__ ws,
                        const float* __restrict__ cluster_size,
                        const float* __restrict__ davg,
                        float* __restrict__ out) {
    __shared__ float red[16];
    __shared__ float nsh;
    const int j = threadIdx.x;

    float cnt = ws[WS_COUNTS + j];
    float ncs = DECAYF * cluster_size[j] + OMD * cnt;
    out[O3 + j] = ncs;

    float v = ncs;
    #pragma unroll
    for (int off = 32; off > 0; off >>= 1) v += __shfl_down(v, off);
    if ((j & 63) == 0) red[j >> 6] = v;
    __syncthreads();
    if (j == 0) {
        float t = 0.f;
        #pragma unroll
        for (int w = 0; w < 8; ++w) t += red[w];
        nsh = t;
    }
    __syncthreads();
    const float n = nsh;
    const float csj = (ncs + EPSF) / (n + NE * EPSF) * n;

    float asum = 0.f;
    #pragma unroll
    for (int c = 0; c < DIMC; ++c) {
        float es = ws[WS_ESUM + c * NE + j];
        float da = davg[c * NE + j];
        float nda = DECAYF * da + OMD * es;
        out[O4 + c * NE + j] = nda;
        float nd = nda / csj;
        out[O5 + c * NE + j] = nd;
        asum += fabsf(nd);
    }

    __syncthreads();
    #pragma unroll
    for (int off = 32; off > 0; off >>= 1) asum += __shfl_down(asum, off);
    if ((j & 63) == 0) red[j >> 6] = asum;
    __syncthreads();
    if (j == 0) {
        float t = 0.f;
        #pragma unroll
        for (int w = 0; w < 8; ++w) t += red[w];
        out[O6] = t / 32768.0f;
        out[O1] = ws[WS_DIFF] / 8388608.0f;
    }
}

extern "C" void kernel_launch(void* const* d_in, const int* in_sizes, int n_in,
                              void* d_out, int out_size, void* d_ws, size_t ws_size,
                              hipStream_t stream) {
    const float* x    = (const float*)d_in[0];
    const float* dict = (const float*)d_in[1];
    const float* csz  = (const float*)d_in[2];
    const float* davg = (const float*)d_in[3];
    float* out = (float*)d_out;
    float* ws  = (float*)d_ws;

    const int use_part = (ws_size >= WS_NEED_BYTES) ? 1 : 0;

    // zero diff + esum + counts (needed for atomic fallback; k_reduce
    // fully overwrites them when use_part)
    hipMemsetAsync(ws, 0, (size_t)(WS_ESUM + 32768 + 512) * sizeof(float), stream);

    k_prep<<<512, 64, 0, stream>>>(dict, ws);

    const int lds_bytes = (32768 + 512 + 8) * 4;
    hipFuncSetAttribute((const void*)k_assign,
                        hipFuncAttributeMaxDynamicSharedMemorySize, lds_bytes);
    k_assign<<<NBLK, 512, lds_bytes, stream>>>(x, ws, out, use_part);

    if (use_part) k_reduce<<<65, 128, 0, stream>>>(ws);

    k_final<<<1, 512, 0, stream>>>(ws, csz, davg, out);
}

// Round 7
// 328.860 us; speedup vs baseline: 1.2021x; 1.2021x over previous
//
#include <hip/hip_runtime.h>
#include <math.h>

#define DIMC 64
#define NE 512
#define HWSZ 4096              // 64*64
#define DECAYF 0.99f
#define OMD 0.01f
#define EPSF 1e-5f
#define MARGIN 1e-3f

// output offsets (floats) — out0 is [32,64,64,64] = 8388608 elements
#define O0 0
#define O1 8388608                 // diff scalar
#define O2 8388609                 // embed_ind [32,64,64]
#define O3 8519681                 // new_cluster_size [512]
#define O4 8520193                 // new_dictionary_avg [64,512]
#define O5 8552961                 // new_dictionary [64,512]
#define O6 8585729                 // mean_D scalar

// ws float layout
#define WS_DIFF   0
#define WS_ESUM   64                       // [c][j] 64*512 (reduced)
#define WS_COUNTS (64+32768)               // 512 (reduced)
#define WS_DT     (64+32768+512)           // [j][c] transposed dict f32, 32768
#define WS_NORM   (WS_DT+32768)            // 512: -0.5*||d_j||^2
#define WS_DHI    (WS_NORM+512)            // 512x64 bf16 (16384 floats)
#define WS_DLO    (WS_DHI+16384)           // 512x64 bf16
#define WS_PART   (WS_DLO+16384)           // NBLK x 33280 partials
#define PART_STRIDE 33280                  // 32768 esum + 512 counts
#define NBLK 256
#define WS_NEED_BYTES ((size_t)(WS_PART + (size_t)NBLK * PART_STRIDE) * 4)

typedef __attribute__((ext_vector_type(8))) short bf16x8;
typedef __attribute__((ext_vector_type(4))) float f32x4;

__device__ __forceinline__ unsigned bf16rne(float x) {
    unsigned u = __float_as_uint(x);
    return (u + 0x7FFFu + ((u >> 16) & 1u)) >> 16;
}

// -------- K1: dictT f32 + bf16 hi/lo split + negated half-norms --------
__global__ void k_prep(const float* __restrict__ dict, float* __restrict__ ws) {
    int j = blockIdx.x, c = threadIdx.x;
    float v = dict[c * NE + j];
    ws[WS_DT + j * DIMC + c] = v;
    unsigned h = bf16rne(v);
    float fh = __uint_as_float(h << 16);
    unsigned l = bf16rne(v - fh);
    ((unsigned short*)(ws + WS_DHI))[j * DIMC + c] = (unsigned short)h;
    ((unsigned short*)(ws + WS_DLO))[j * DIMC + c] = (unsigned short)l;
    float s = v * v;
    #pragma unroll
    for (int off = 32; off > 0; off >>= 1) s += __shfl_down(s, off);
    if (c == 0) ws[WS_NORM + j] = -0.5f * s;
}

#define MFMA16(A, B, C) __builtin_amdgcn_mfma_f32_16x16x32_bf16(A, B, C, 0, 0, 0)

// -------- K2: MFMA assignment + margin-certified argmax + stats --------
// 256 blocks x 512 threads (8 waves); each wave computes 64 points x 512 codes.
__global__ __launch_bounds__(512, 2) void k_assign(
        const float* __restrict__ x, float* __restrict__ ws,
        float* __restrict__ out, int use_part) {
    extern __shared__ float lds[];
    char*  ldsB  = (char*)lds;          // phase1: fhi[512][64]bf16 | flo (128KB)
    float* esum  = lds;                 // phase2: esum_t [c][j] 64x512 f32
    int*   lhist = (int*)(lds + 32768); // 512
    int*   bidxl = (int*)(lds + 33280); // 512
    float* lred  = lds + 33792;         // 8

    const int tid  = threadIdx.x;
    const int lane = tid & 63;
    const int w    = tid >> 6;

    const int n0 = blockIdx.x * 512 + tid;
    const int b = n0 >> 12, hw0 = n0 & 4095;
    const float* xp = x + (size_t)b * (DIMC * HWSZ) + hw0;

    // ---- load point + bf16 split + stage to LDS (chunk-XOR swizzled) ----
    float f0[DIMC];
    #pragma unroll
    for (int c = 0; c < DIMC; ++c) f0[c] = xp[c * HWSZ];
    {
        unsigned hiw[32], low[32];
        #pragma unroll
        for (int i = 0; i < 32; ++i) {
            unsigned h0 = bf16rne(f0[2 * i]);
            unsigned h1 = bf16rne(f0[2 * i + 1]);
            float fh0 = __uint_as_float(h0 << 16);
            float fh1 = __uint_as_float(h1 << 16);
            unsigned l0 = bf16rne(f0[2 * i] - fh0);
            unsigned l1 = bf16rne(f0[2 * i + 1] - fh1);
            hiw[i] = h0 | (h1 << 16);
            low[i] = l0 | (l1 << 16);
        }
        const int swz = tid & 7;
        #pragma unroll
        for (int k = 0; k < 8; ++k) {
            uint4 vh = {hiw[4 * k], hiw[4 * k + 1], hiw[4 * k + 2], hiw[4 * k + 3]};
            uint4 vl = {low[4 * k], low[4 * k + 1], low[4 * k + 2], low[4 * k + 3]};
            *(uint4*)(ldsB + tid * 128 + ((k ^ swz) << 4)) = vh;
            *(uint4*)(ldsB + 65536 + tid * 128 + ((k ^ swz) << 4)) = vl;
        }
    }
    lhist[tid] = 0;
    __syncthreads();

    // ---- A-fragments into registers (own wave's 64 rows only) ----
    // A layout (16x16x32): row = lane&15, k = (lane>>4)*8 + e  (+32*kk)
    bf16x8 ahi[4][2], alo[4][2];
    #pragma unroll
    for (int pt = 0; pt < 4; ++pt) {
        const int arow = (w << 6) + (pt << 4) + (lane & 15);
        const int swz = arow & 7;
        #pragma unroll
        for (int kk = 0; kk < 2; ++kk) {
            const int ch = (lane >> 4) + (kk << 2);
            ahi[pt][kk] = __builtin_bit_cast(bf16x8,
                *(const uint4*)(ldsB + arow * 128 + ((ch ^ swz) << 4)));
            alo[pt][kk] = __builtin_bit_cast(bf16x8,
                *(const uint4*)(ldsB + 65536 + arow * 128 + ((ch ^ swz) << 4)));
        }
    }
    __syncthreads();   // all frag reads done -> LDS reusable as esum

    // zero esum region (overwrites fhi/flo)
    {
        float4 z = {0.f, 0.f, 0.f, 0.f};
        float4* e4 = (float4*)lds;
        #pragma unroll
        for (int k = 0; k < 16; ++k) e4[tid + 512 * k] = z;
    }

    // ---- MFMA sweep over 32 code-tiles ----
    const uint4* dh4 = (const uint4*)(ws + WS_DHI);
    const uint4* dl4 = (const uint4*)(ws + WS_DLO);
    const float* npl = ws + WS_NORM + (lane & 15);
    const int bl = ((lane & 15) << 3) + (lane >> 4);   // uint4 units

    float best[4][4], sec[4][4];
    int   idx[4][4];
    #pragma unroll
    for (int pt = 0; pt < 4; ++pt)
        #pragma unroll
        for (int r = 0; r < 4; ++r) {
            best[pt][r] = -3.4e38f; sec[pt][r] = -3.4e38f; idx[pt][r] = 0;
        }

    #pragma unroll 2
    for (int jt = 0; jt < 32; ++jt) {
        uint4 uh0 = dh4[(jt << 7) + bl];
        uint4 uh1 = dh4[(jt << 7) + bl + 4];
        uint4 ul0 = dl4[(jt << 7) + bl];
        uint4 ul1 = dl4[(jt << 7) + bl + 4];
        float nrm = npl[jt << 4];
        bf16x8 bh0 = __builtin_bit_cast(bf16x8, uh0);
        bf16x8 bh1 = __builtin_bit_cast(bf16x8, uh1);
        bf16x8 bl0 = __builtin_bit_cast(bf16x8, ul0);
        bf16x8 bl1 = __builtin_bit_cast(bf16x8, ul1);
        const int jc = (jt << 4) + (lane & 15);
        #pragma unroll
        for (int pt = 0; pt < 4; ++pt) {
            f32x4 acc = {0.f, 0.f, 0.f, 0.f};
            acc = MFMA16(ahi[pt][0], bh0, acc);
            acc = MFMA16(ahi[pt][1], bh1, acc);
            acc = MFMA16(ahi[pt][0], bl0, acc);
            acc = MFMA16(ahi[pt][1], bl1, acc);
            acc = MFMA16(alo[pt][0], bh0, acc);
            acc = MFMA16(alo[pt][1], bh1, acc);
            acc = MFMA16(alo[pt][0], bl0, acc);
            acc = MFMA16(alo[pt][1], bl1, acc);
            #pragma unroll
            for (int r = 0; r < 4; ++r) {
                float s = acc[r] + nrm;
                bool gt = s > best[pt][r];
                float ns = gt ? best[pt][r] : (s > sec[pt][r] ? s : sec[pt][r]);
                best[pt][r] = gt ? s : best[pt][r];
                idx[pt][r]  = gt ? jc : idx[pt][r];
                sec[pt][r]  = ns;
            }
        }
    }

    // ---- argmax reduce across 16-lane code groups (carry best, sec, idx) ----
    #pragma unroll
    for (int off = 8; off > 0; off >>= 1) {
        #pragma unroll
        for (int pt = 0; pt < 4; ++pt)
            #pragma unroll
            for (int r = 0; r < 4; ++r) {
                float ob = __shfl_xor(best[pt][r], off, 16);
                float os = __shfl_xor(sec[pt][r], off, 16);
                int   oi = __shfl_xor(idx[pt][r], off, 16);
                bool take = (ob > best[pt][r]) ||
                            (ob == best[pt][r] && oi < idx[pt][r]);
                float nsec = fmaxf(fminf(ob, best[pt][r]),
                                   fmaxf(os, sec[pt][r]));
                best[pt][r] = take ? ob : best[pt][r];
                idx[pt][r]  = take ? oi : idx[pt][r];
                sec[pt][r]  = nsec;
            }
    }
    if ((lane & 15) == 0) {
        const int g = lane >> 4;
        #pragma unroll
        for (int pt = 0; pt < 4; ++pt)
            #pragma unroll
            for (int r = 0; r < 4; ++r) {
                int p = (w << 6) + (pt << 4) + (g << 2) + r;
                int flag = (best[pt][r] - sec[pt][r] < MARGIN) ? 65536 : 0;
                bidxl[p] = idx[pt][r] | flag;
            }
    }
    __syncthreads();

    int ent = bidxl[tid];
    int bi0 = ent & 511;

    const float* dptr = ws + WS_DT;
    if (ent & 65536) {
        // exact fp32 rescan (same fmaf chain as the passing r5/r6 kernels)
        const float* nptr = ws + WS_NORM;
        float bb = -3.4e38f; int bj = 0;
        #pragma unroll 2
        for (int j = 0; j < NE; ++j) {
            const float4* row = (const float4*)(dptr + (size_t)j * DIMC);
            float a0 = 0.f, a1 = 0.f, a2 = 0.f, a3 = 0.f;
            #pragma unroll
            for (int c4 = 0; c4 < 16; ++c4) {
                float4 r4 = row[c4];
                const int cb = 4 * c4;
                a0 = fmaf(r4.x, f0[cb + 0], a0);
                a1 = fmaf(r4.y, f0[cb + 1], a1);
                a2 = fmaf(r4.z, f0[cb + 2], a2);
                a3 = fmaf(r4.w, f0[cb + 3], a3);
            }
            float sc = ((a0 + a1) + (a2 + a3)) + nptr[j];
            if (sc > bb) { bb = sc; bj = j; }
        }
        bi0 = bj;
    }

    // ---- epilogue (same as r6) ----
    atomicAdd(&lhist[bi0], 1);
    out[O2 + n0] = (float)bi0;

    float ssum = 0.f;
    float* o0 = out + O0 + (size_t)b * (DIMC * HWSZ) + hw0;
    const float4* q40 = (const float4*)(dptr + (size_t)bi0 * DIMC);
    #pragma unroll
    for (int c4 = 0; c4 < 16; ++c4) {
        float4 qa = q40[c4];
        const int cb = 4 * c4;
        o0[(cb + 0) * HWSZ] = qa.x;
        o0[(cb + 1) * HWSZ] = qa.y;
        o0[(cb + 2) * HWSZ] = qa.z;
        o0[(cb + 3) * HWSZ] = qa.w;
        float d;
        d = qa.x - f0[cb + 0]; ssum = fmaf(d, d, ssum);
        d = qa.y - f0[cb + 1]; ssum = fmaf(d, d, ssum);
        d = qa.z - f0[cb + 2]; ssum = fmaf(d, d, ssum);
        d = qa.w - f0[cb + 3]; ssum = fmaf(d, d, ssum);
    }

    // scatter: banks spread by bidx (esum[c*512 + j], bank = j & 31)
    #pragma unroll
    for (int c = 0; c < DIMC; ++c) atomicAdd(&esum[c * NE + bi0], f0[c]);
    __syncthreads();

    if (use_part) {
        float* part = ws + WS_PART + (size_t)blockIdx.x * PART_STRIDE;
        float4* p4 = (float4*)part;
        const float4* e4 = (const float4*)esum;
        #pragma unroll
        for (int k = 0; k < 16; ++k) p4[tid + 512 * k] = e4[tid + 512 * k];
        part[32768 + tid] = (float)lhist[tid];
    } else {
        #pragma unroll
        for (int k = 0; k < 64; ++k)
            atomicAdd(&ws[WS_ESUM + tid + 512 * k], esum[tid + 512 * k]);
        atomicAdd(&ws[WS_COUNTS + tid], (float)lhist[tid]);
    }

    // diff reduction (8 waves)
    #pragma unroll
    for (int off = 32; off > 0; off >>= 1) ssum += __shfl_down(ssum, off);
    if ((tid & 63) == 0) lred[tid >> 6] = ssum;
    __syncthreads();
    if (tid == 0) {
        float t = 0.f;
        #pragma unroll
        for (int w2 = 0; w2 < 8; ++w2) t += lred[w2];
        atomicAdd(ws + WS_DIFF, t);
    }
}

// -------- K2b: tree-reduce per-block partials into WS_ESUM/WS_COUNTS --------
__global__ void k_reduce(float* __restrict__ ws) {
    const int gid = blockIdx.x * 128 + threadIdx.x;   // [0, 8320)
    const float4* src = (const float4*)(ws + WS_PART);
    float4 acc = {0.f, 0.f, 0.f, 0.f};
    #pragma unroll 4
    for (int p = 0; p < NBLK; ++p) {
        float4 v = src[(size_t)p * (PART_STRIDE / 4) + gid];
        acc.x += v.x; acc.y += v.y; acc.z += v.z; acc.w += v.w;
    }
    ((float4*)(ws + WS_ESUM))[gid] = acc;
}

// -------- K3: finalize EMA buffers / outputs --------
__global__ void k_final(const float* __restrict__ ws,
                        const float* __restrict__ cluster_size,
                        const float* __restrict__ davg,
                        float* __restrict__ out) {
    __shared__ float red[16];
    __shared__ float nsh;
    const int j = threadIdx.x;

    float cnt = ws[WS_COUNTS + j];
    float ncs = DECAYF * cluster_size[j] + OMD * cnt;
    out[O3 + j] = ncs;

    float v = ncs;
    #pragma unroll
    for (int off = 32; off > 0; off >>= 1) v += __shfl_down(v, off);
    if ((j & 63) == 0) red[j >> 6] = v;
    __syncthreads();
    if (j == 0) {
        float t = 0.f;
        #pragma unroll
        for (int w = 0; w < 8; ++w) t += red[w];
        nsh = t;
    }
    __syncthreads();
    const float n = nsh;
    const float csj = (ncs + EPSF) / (n + NE * EPSF) * n;

    float asum = 0.f;
    #pragma unroll
    for (int c = 0; c < DIMC; ++c) {
        float es = ws[WS_ESUM + c * NE + j];
        float da = davg[c * NE + j];
        float nda = DECAYF * da + OMD * es;
        out[O4 + c * NE + j] = nda;
        float nd = nda / csj;
        out[O5 + c * NE + j] = nd;
        asum += fabsf(nd);
    }

    __syncthreads();
    #pragma unroll
    for (int off = 32; off > 0; off >>= 1) asum += __shfl_down(asum, off);
    if ((j & 63) == 0) red[j >> 6] = asum;
    __syncthreads();
    if (j == 0) {
        float t = 0.f;
        #pragma unroll
        for (int w = 0; w < 8; ++w) t += red[w];
        out[O6] = t / 32768.0f;
        out[O1] = ws[WS_DIFF] / 8388608.0f;
    }
}

extern "C" void kernel_launch(void* const* d_in, const int* in_sizes, int n_in,
                              void* d_out, int out_size, void* d_ws, size_t ws_size,
                              hipStream_t stream) {
    const float* x    = (const float*)d_in[0];
    const float* dict = (const float*)d_in[1];
    const float* csz  = (const float*)d_in[2];
    const float* davg = (const float*)d_in[3];
    float* out = (float*)d_out;
    float* ws  = (float*)d_ws;

    const int use_part = (ws_size >= WS_NEED_BYTES) ? 1 : 0;

    // zero diff + esum + counts (needed for atomic fallback; k_reduce
    // fully overwrites them when use_part)
    hipMemsetAsync(ws, 0, (size_t)(WS_ESUM + 32768 + 512) * sizeof(float), stream);

    k_prep<<<512, 64, 0, stream>>>(dict, ws);

    const int lds_bytes = 33800 * 4;
    hipFuncSetAttribute((const void*)k_assign,
                        hipFuncAttributeMaxDynamicSharedMemorySize, lds_bytes);
    k_assign<<<NBLK, 512, lds_bytes, stream>>>(x, ws, out, use_part);

    if (use_part) k_reduce<<<65, 128, 0, stream>>>(ws);

    k_final<<<1, 512, 0, stream>>>(ws, csz, davg, out);
}